// Round 1
// baseline (1729.992 us; speedup 1.0000x reference)
//
#include <hip/hip_runtime.h>

#define SEQ 8192
#define DIM 1024
#define SM_SCALE 0.03125f   // 1/sqrt(1024)

typedef unsigned short u16;
typedef float f32x4 __attribute__((ext_vector_type(4)));
typedef short bf16x8 __attribute__((ext_vector_type(8)));
typedef u16   u16x4 __attribute__((ext_vector_type(4)));

__device__ __forceinline__ u16 f2bf(float x) {
    unsigned u = __float_as_uint(x);
    u += 0x7fffu + ((u >> 16) & 1u);           // round-to-nearest-even
    return (u16)(u >> 16);
}
__device__ __forceinline__ float bf2f(u16 b) {
    return __uint_as_float(((unsigned)b) << 16);
}

// ---------------------------------------------------------------------------
// Split fp32 -> (hi,lo) bf16, optionally also writing the transposed copies.
// src [R][C] f32.  hiNT/loNT: [R][C] bf16.  hiT/loT: [C][R] bf16.
// grid = (C/32, R/32), block = 256
// ---------------------------------------------------------------------------
template<bool WRITE_NT>
__launch_bounds__(256)
__global__ void split_kernel(const float* __restrict__ src, int R, int C,
                             u16* __restrict__ hiNT, u16* __restrict__ loNT,
                             u16* __restrict__ hiT,  u16* __restrict__ loT)
{
    __shared__ u16 th[32][33];
    __shared__ u16 tl[32][33];
    int tx = threadIdx.x & 31;
    int ty = threadIdx.x >> 5;           // 0..7
    int c0 = blockIdx.x * 32;
    int r0 = blockIdx.y * 32;
#pragma unroll
    for (int k = 0; k < 4; ++k) {
        int r = ty + k * 8;
        float x = src[(size_t)(r0 + r) * C + c0 + tx];
        u16 h = f2bf(x);
        u16 lo = f2bf(x - bf2f(h));
        if constexpr (WRITE_NT) {
            hiNT[(size_t)(r0 + r) * C + c0 + tx] = h;
            loNT[(size_t)(r0 + r) * C + c0 + tx] = lo;
        }
        th[r][tx] = h;
        tl[r][tx] = lo;
    }
    __syncthreads();
#pragma unroll
    for (int k = 0; k < 4; ++k) {
        int cc = ty + k * 8;
        hiT[(size_t)(c0 + cc) * R + r0 + tx] = th[tx][cc];
        loT[(size_t)(c0 + cc) * R + r0 + tx] = tl[tx][cc];
    }
}

// ---------------------------------------------------------------------------
// NT GEMM with split-bf16 fp32 emulation.
//   NTERMS==3:  C = A0@B0^T + A0@B1^T + A1@B0^T   (A=hi/lo, B=hi/lo)
//   NTERMS==2:  C = A0@B0^T + A0@B1^T             (A single, B=hi/lo sum)
//   OUTMODE==0: write fp32 C
//   OUTMODE==1: write C split into (Ch,Cl) bf16
// A* : [M][K] bf16 row-major.  B* : [N][K] bf16 row-major (i.e. B^T form).
// grid = (N/128, M/128), block = 256 (4 waves, each computes 64x64)
// ---------------------------------------------------------------------------
#define BM 128
#define BN 128
#define BK 32
#define LDT (BK + 8)   // padded LDS row (shorts) -> conflict-free ds_read_b128

template<int NTERMS, int OUTMODE>
__launch_bounds__(256)
__global__ void gemm_nt(const u16* __restrict__ A0, const u16* __restrict__ A1,
                        const u16* __restrict__ B0, const u16* __restrict__ B1,
                        int M, int N, int K,
                        float* __restrict__ Cf,
                        u16* __restrict__ Ch, u16* __restrict__ Cl)
{
    __shared__ u16 sA0[BM][LDT];
    __shared__ u16 sB0[BN][LDT];
    __shared__ u16 sB1[BN][LDT];
    __shared__ u16 sA1[(NTERMS == 3) ? BM : 1][LDT];

    int t = threadIdx.x;
    int w = t >> 6, l = t & 63;
    int wr = (w >> 1) * 64, wc = (w & 1) * 64;
    int lr = l & 15;              // fragment row (m or n within 16)
    int lk = (l >> 4) * 8;        // fragment k-offset
    int m0 = blockIdx.y * BM, n0 = blockIdx.x * BN;

    int sr = t >> 2;              // staging row (i adds 64)
    int sc = (t & 3) * 8;         // staging col

    f32x4 acc[4][4];
#pragma unroll
    for (int i = 0; i < 4; ++i)
#pragma unroll
        for (int j = 0; j < 4; ++j) acc[i][j] = (f32x4){0.f, 0.f, 0.f, 0.f};

    for (int k0 = 0; k0 < K; k0 += BK) {
        bf16x8 va0[2], va1[2], vb0[2], vb1[2];
#pragma unroll
        for (int i = 0; i < 2; ++i) {
            int r = sr + i * 64;
            va0[i] = *(const bf16x8*)&A0[(size_t)(m0 + r) * K + k0 + sc];
            if constexpr (NTERMS == 3)
                va1[i] = *(const bf16x8*)&A1[(size_t)(m0 + r) * K + k0 + sc];
            vb0[i] = *(const bf16x8*)&B0[(size_t)(n0 + r) * K + k0 + sc];
            vb1[i] = *(const bf16x8*)&B1[(size_t)(n0 + r) * K + k0 + sc];
        }
        __syncthreads();          // previous iter's LDS reads complete
#pragma unroll
        for (int i = 0; i < 2; ++i) {
            int r = sr + i * 64;
            *(bf16x8*)&sA0[r][sc] = va0[i];
            if constexpr (NTERMS == 3) *(bf16x8*)&sA1[r][sc] = va1[i];
            *(bf16x8*)&sB0[r][sc] = vb0[i];
            *(bf16x8*)&sB1[r][sc] = vb1[i];
        }
        __syncthreads();

        bf16x8 fa0[4], fa1[4], fb0[4], fb1[4];
#pragma unroll
        for (int m = 0; m < 4; ++m) {
            fa0[m] = *(const bf16x8*)&sA0[wr + m * 16 + lr][lk];
            if constexpr (NTERMS == 3)
                fa1[m] = *(const bf16x8*)&sA1[wr + m * 16 + lr][lk];
        }
#pragma unroll
        for (int n = 0; n < 4; ++n) {
            fb0[n] = *(const bf16x8*)&sB0[wc + n * 16 + lr][lk];
            fb1[n] = *(const bf16x8*)&sB1[wc + n * 16 + lr][lk];
        }
#pragma unroll
        for (int m = 0; m < 4; ++m)
#pragma unroll
            for (int n = 0; n < 4; ++n) {
                acc[m][n] = __builtin_amdgcn_mfma_f32_16x16x32_bf16(fa0[m], fb0[n], acc[m][n], 0, 0, 0);
                acc[m][n] = __builtin_amdgcn_mfma_f32_16x16x32_bf16(fa0[m], fb1[n], acc[m][n], 0, 0, 0);
                if constexpr (NTERMS == 3)
                    acc[m][n] = __builtin_amdgcn_mfma_f32_16x16x32_bf16(fa1[m], fb0[n], acc[m][n], 0, 0, 0);
            }
    }

    // Epilogue. C/D frag mapping (verified m89): col = lane&15, row = (lane>>4)*4 + reg
    int orow = m0 + wr + (l >> 4) * 4;
    int ocol = n0 + wc + (l & 15);
#pragma unroll
    for (int m = 0; m < 4; ++m)
#pragma unroll
        for (int n = 0; n < 4; ++n)
#pragma unroll
            for (int q = 0; q < 4; ++q) {
                size_t idx = (size_t)(orow + m * 16 + q) * N + (ocol + n * 16);
                float v = acc[m][n][q];
                if constexpr (OUTMODE == 0) {
                    Cf[idx] = v;
                } else {
                    u16 h = f2bf(v);
                    Ch[idx] = h;
                    Cl[idx] = f2bf(v - bf2f(h));
                }
            }
}

// ---------------------------------------------------------------------------
// Row softmax: P[r][:] = softmax(S[r][:] * SM_SCALE), fp32 -> bf16
// grid = (#rows), block = 256
// ---------------------------------------------------------------------------
__launch_bounds__(256)
__global__ void softmax_kernel(const float* __restrict__ S, u16* __restrict__ P)
{
    size_t row = blockIdx.x;
    const f32x4* s4 = (const f32x4*)(S + row * SEQ);
    int t = threadIdx.x;
    int w = t >> 6, l = t & 63;

    float v[32];
    float mx = -3.4e38f;
#pragma unroll
    for (int i = 0; i < 8; ++i) {
        f32x4 x = s4[t + i * 256];
#pragma unroll
        for (int j = 0; j < 4; ++j) {
            float f = x[j] * SM_SCALE;
            v[i * 4 + j] = f;
            mx = fmaxf(mx, f);
        }
    }
#pragma unroll
    for (int off = 32; off; off >>= 1) mx = fmaxf(mx, __shfl_xor(mx, off));

    __shared__ float redm[4];
    __shared__ float reds[4];
    if (l == 0) redm[w] = mx;
    __syncthreads();
    mx = fmaxf(fmaxf(redm[0], redm[1]), fmaxf(redm[2], redm[3]));

    float sum = 0.f;
#pragma unroll
    for (int i = 0; i < 32; ++i) {
        v[i] = __expf(v[i] - mx);
        sum += v[i];
    }
#pragma unroll
    for (int off = 32; off; off >>= 1) sum += __shfl_xor(sum, off);
    if (l == 0) reds[w] = sum;
    __syncthreads();
    sum = reds[0] + reds[1] + reds[2] + reds[3];
    float inv = 1.f / sum;

    u16* p = P + row * SEQ;
#pragma unroll
    for (int i = 0; i < 8; ++i) {
        u16x4 o;
#pragma unroll
        for (int j = 0; j < 4; ++j) o[j] = f2bf(v[i * 4 + j] * inv);
        *(u16x4*)&p[4 * (t + i * 256)] = o;
    }
}

// ---------------------------------------------------------------------------
extern "C" void kernel_launch(void* const* d_in, const int* in_sizes, int n_in,
                              void* d_out, int out_size, void* d_ws, size_t ws_size,
                              hipStream_t stream)
{
    const float* X  = (const float*)d_in[0];
    const float* Wq = (const float*)d_in[1];
    const float* Wk = (const float*)d_in[2];
    float* out = (float*)d_out;
    char* ws = (char*)d_ws;

    const size_t XE = (size_t)SEQ * DIM;   // 8 Mi elements
    const size_t WE = (size_t)DIM * DIM;   // 1 Mi elements

    u16* Xh   = (u16*)ws;
    u16* Xl   = Xh + XE;
    u16* XhT  = Xl + XE;
    u16* XlT  = XhT + XE;
    u16* WqhT = XlT + XE;
    u16* WqlT = WqhT + WE;
    u16* WkhT = WqlT + WE;
    u16* WklT = WkhT + WE;
    u16* Qh   = WklT + WE;
    u16* Ql   = Qh + XE;
    u16* Kh   = Ql + XE;
    u16* Kl   = Kh + XE;
    char* dyn = (char*)(Kl + XE);

    size_t fixed = (size_t)(dyn - ws);
    size_t avail = ws_size > fixed ? ws_size - fixed : 0;
    size_t perrow = (size_t)SEQ * 6;       // 4B S + 2B P per row
    long long chll = (long long)(avail / perrow);
    int CH = chll > SEQ ? SEQ : (int)chll;
    CH &= ~127;                            // multiple of 128
    if (CH < 128) CH = 128;                // last-resort (needs ~149MB ws)

    float* Sbuf = (float*)dyn;
    u16*   Pbuf = (u16*)(dyn + (size_t)CH * SEQ * sizeof(float));

    // 1) splits
    split_kernel<true ><<<dim3(DIM / 32, SEQ / 32), 256, 0, stream>>>(X, SEQ, DIM, Xh, Xl, XhT, XlT);
    split_kernel<false><<<dim3(DIM / 32, DIM / 32), 256, 0, stream>>>(Wq, DIM, DIM, nullptr, nullptr, WqhT, WqlT);
    split_kernel<false><<<dim3(DIM / 32, DIM / 32), 256, 0, stream>>>(Wk, DIM, DIM, nullptr, nullptr, WkhT, WklT);

    // 2) projections: Q = X@Wq, K = X@Wk  (fp32-accurate, written as hi/lo bf16)
    gemm_nt<3, 1><<<dim3(DIM / BN, SEQ / BM), 256, 0, stream>>>(
        Xh, Xl, WqhT, WqlT, SEQ, DIM, DIM, nullptr, Qh, Ql);
    gemm_nt<3, 1><<<dim3(DIM / BN, SEQ / BM), 256, 0, stream>>>(
        Xh, Xl, WkhT, WklT, SEQ, DIM, DIM, nullptr, Kh, Kl);

    // 3) chunked S = Q K^T ; P = softmax(S/32) ; out = P V (V = X)
    for (int r0 = 0; r0 < SEQ; r0 += CH) {
        int ch = (SEQ - r0 < CH) ? (SEQ - r0) : CH;
        gemm_nt<3, 0><<<dim3(SEQ / BN, ch / BM), 256, 0, stream>>>(
            Qh + (size_t)r0 * DIM, Ql + (size_t)r0 * DIM, Kh, Kl,
            ch, SEQ, DIM, Sbuf, nullptr, nullptr);
        softmax_kernel<<<ch, 256, 0, stream>>>(Sbuf, Pbuf);
        gemm_nt<2, 0><<<dim3(DIM / BN, ch / BM), 256, 0, stream>>>(
            Pbuf, nullptr, XhT, XlT,
            ch, DIM, SEQ, out + (size_t)r0 * DIM, nullptr, nullptr);
    }
}

// Round 2
// 1672.589 us; speedup vs baseline: 1.0343x; 1.0343x over previous
//
#include <hip/hip_runtime.h>

#define SEQ 8192
#define DIM 1024
#define SM_SCALE 0.03125f   // 1/sqrt(1024)

typedef unsigned short u16;
typedef float f32x4 __attribute__((ext_vector_type(4)));
typedef short bf16x8 __attribute__((ext_vector_type(8)));
typedef u16   u16x4 __attribute__((ext_vector_type(4)));

typedef __attribute__((address_space(1))) void as1_void;
typedef __attribute__((address_space(3))) void as3_void;

__device__ __forceinline__ u16 f2bf(float x) {
    unsigned u = __float_as_uint(x);
    u += 0x7fffu + ((u >> 16) & 1u);           // round-to-nearest-even
    return (u16)(u >> 16);
}
__device__ __forceinline__ float bf2f(u16 b) {
    return __uint_as_float(((unsigned)b) << 16);
}

// async global->LDS, 16B per lane. LDS dest must be wave-uniform-base + lane*16.
__device__ __forceinline__ void gload16(const void* g, void* l) {
    __builtin_amdgcn_global_load_lds((as1_void*)(void*)(size_t)g, (as3_void*)l, 16, 0, 0);
}

// ---------------------------------------------------------------------------
// Split fp32 -> (hi,lo) bf16, optionally also writing the transposed copies.
// ---------------------------------------------------------------------------
template<bool WRITE_NT>
__launch_bounds__(256)
__global__ void split_kernel(const float* __restrict__ src, int R, int C,
                             u16* __restrict__ hiNT, u16* __restrict__ loNT,
                             u16* __restrict__ hiT,  u16* __restrict__ loT)
{
    __shared__ u16 th[32][33];
    __shared__ u16 tl[32][33];
    int tx = threadIdx.x & 31;
    int ty = threadIdx.x >> 5;           // 0..7
    int c0 = blockIdx.x * 32;
    int r0 = blockIdx.y * 32;
#pragma unroll
    for (int k = 0; k < 4; ++k) {
        int r = ty + k * 8;
        float x = src[(size_t)(r0 + r) * C + c0 + tx];
        u16 h = f2bf(x);
        u16 lo = f2bf(x - bf2f(h));
        if constexpr (WRITE_NT) {
            hiNT[(size_t)(r0 + r) * C + c0 + tx] = h;
            loNT[(size_t)(r0 + r) * C + c0 + tx] = lo;
        }
        th[r][tx] = h;
        tl[r][tx] = lo;
    }
    __syncthreads();
#pragma unroll
    for (int k = 0; k < 4; ++k) {
        int cc = ty + k * 8;
        hiT[(size_t)(c0 + cc) * R + r0 + tx] = th[tx][cc];
        loT[(size_t)(c0 + cc) * R + r0 + tx] = tl[tx][cc];
    }
}

// ---------------------------------------------------------------------------
// NT GEMM, split-bf16 fp32 emulation, m97 structure:
// global_load_lds(w=16) -> linear LDS, 2 barriers/K-step, 4 waves, 128x128.
//   NTERMS==3:  C = A0@B0^T + A0@B1^T + A1@B0^T
//   NTERMS==2:  C = A0@B0^T + A0@B1^T
//   OUTMODE==0: fp32 C    OUTMODE==1: C split into (Ch,Cl) bf16
// A*: [M][K] bf16 row-major.  B*: [N][K] bf16 row-major (B^T form).
// grid = (N/128, M/128), block = 256
// ---------------------------------------------------------------------------
#define BM 128
#define BN 128
#define BK 32

template<int NTERMS, int OUTMODE>
__launch_bounds__(256)
__global__ void gemm_nt(const u16* __restrict__ A0, const u16* __restrict__ A1,
                        const u16* __restrict__ B0, const u16* __restrict__ B1,
                        int M, int N, int K,
                        float* __restrict__ Cf,
                        u16* __restrict__ Ch, u16* __restrict__ Cl)
{
    __shared__ u16 sA0[BM * BK];                       // 8KB, linear [row*BK+col]
    __shared__ u16 sB0[BN * BK];
    __shared__ u16 sB1[BN * BK];
    __shared__ u16 sA1[(NTERMS == 3) ? BM * BK : 64];

    int t = threadIdx.x;
    int w = t >> 6, l = t & 63;
    int wr = (w >> 1) * 64, wc = (w & 1) * 64;
    int lr = l & 15;
    int lk = (l >> 4) * 8;
    int m0 = blockIdx.y * BM, n0 = blockIdx.x * BN;

    // staging: thread t covers (row = t>>2 [+64], col = (t&3)*8) of each tile.
    // LDS element offset = t*8 (+2048)  -> byte = t*16 (+4096): lane-contiguous.
    int srow = t >> 2, scol = (t & 3) * 8;
    const u16* ga0 = A0 + (size_t)(m0 + srow) * K + scol;
    const u16* gb0 = B0 + (size_t)(n0 + srow) * K + scol;
    const u16* gb1 = B1 + (size_t)(n0 + srow) * K + scol;
    const u16* ga1 = (NTERMS == 3) ? A1 + (size_t)(m0 + srow) * K + scol : nullptr;
    const size_t rstep = (size_t)64 * K;

    f32x4 acc[4][4];
#pragma unroll
    for (int i = 0; i < 4; ++i)
#pragma unroll
        for (int j = 0; j < 4; ++j) acc[i][j] = (f32x4){0.f, 0.f, 0.f, 0.f};

    for (int k0 = 0; k0 < K; k0 += BK) {
        __syncthreads();                 // all waves done reading previous tile
        gload16(ga0,         &sA0[t * 8]);
        gload16(ga0 + rstep, &sA0[t * 8 + 2048]);
        gload16(gb0,         &sB0[t * 8]);
        gload16(gb0 + rstep, &sB0[t * 8 + 2048]);
        gload16(gb1,         &sB1[t * 8]);
        gload16(gb1 + rstep, &sB1[t * 8 + 2048]);
        if constexpr (NTERMS == 3) {
            gload16(ga1,         &sA1[t * 8]);
            gload16(ga1 + rstep, &sA1[t * 8 + 2048]);
            ga1 += BK;
        }
        ga0 += BK; gb0 += BK; gb1 += BK;
        __syncthreads();                 // vmcnt(0) drained by compiler -> tile ready

        bf16x8 fa0[4], fa1[4], fb0[4], fb1[4];
#pragma unroll
        for (int m = 0; m < 4; ++m) {
            fa0[m] = *(const bf16x8*)&sA0[(wr + m * 16 + lr) * BK + lk];
            if constexpr (NTERMS == 3)
                fa1[m] = *(const bf16x8*)&sA1[(wr + m * 16 + lr) * BK + lk];
        }
#pragma unroll
        for (int n = 0; n < 4; ++n) {
            fb0[n] = *(const bf16x8*)&sB0[(wc + n * 16 + lr) * BK + lk];
            fb1[n] = *(const bf16x8*)&sB1[(wc + n * 16 + lr) * BK + lk];
        }
#pragma unroll
        for (int m = 0; m < 4; ++m)
#pragma unroll
            for (int n = 0; n < 4; ++n) {
                acc[m][n] = __builtin_amdgcn_mfma_f32_16x16x32_bf16(fa0[m], fb0[n], acc[m][n], 0, 0, 0);
                acc[m][n] = __builtin_amdgcn_mfma_f32_16x16x32_bf16(fa0[m], fb1[n], acc[m][n], 0, 0, 0);
                if constexpr (NTERMS == 3)
                    acc[m][n] = __builtin_amdgcn_mfma_f32_16x16x32_bf16(fa1[m], fb0[n], acc[m][n], 0, 0, 0);
            }
    }

    // Epilogue. C/D frag mapping (verified m89): col = lane&15, row = (lane>>4)*4 + reg
    int orow = m0 + wr + (l >> 4) * 4;
    int ocol = n0 + wc + (l & 15);
#pragma unroll
    for (int m = 0; m < 4; ++m)
#pragma unroll
        for (int n = 0; n < 4; ++n)
#pragma unroll
            for (int q = 0; q < 4; ++q) {
                size_t idx = (size_t)(orow + m * 16 + q) * N + (ocol + n * 16);
                float v = acc[m][n][q];
                if constexpr (OUTMODE == 0) {
                    Cf[idx] = v;
                } else {
                    u16 h = f2bf(v);
                    Ch[idx] = h;
                    Cl[idx] = f2bf(v - bf2f(h));
                }
            }
}

// ---------------------------------------------------------------------------
// Row softmax: P[r][:] = softmax(S[r][:] * SM_SCALE), fp32 -> bf16
// ---------------------------------------------------------------------------
__launch_bounds__(256)
__global__ void softmax_kernel(const float* __restrict__ S, u16* __restrict__ P)
{
    size_t row = blockIdx.x;
    const f32x4* s4 = (const f32x4*)(S + row * SEQ);
    int t = threadIdx.x;
    int w = t >> 6, l = t & 63;

    float v[32];
    float mx = -3.4e38f;
#pragma unroll
    for (int i = 0; i < 8; ++i) {
        f32x4 x = s4[t + i * 256];
#pragma unroll
        for (int j = 0; j < 4; ++j) {
            float f = x[j] * SM_SCALE;
            v[i * 4 + j] = f;
            mx = fmaxf(mx, f);
        }
    }
#pragma unroll
    for (int off = 32; off; off >>= 1) mx = fmaxf(mx, __shfl_xor(mx, off));

    __shared__ float redm[4];
    __shared__ float reds[4];
    if (l == 0) redm[w] = mx;
    __syncthreads();
    mx = fmaxf(fmaxf(redm[0], redm[1]), fmaxf(redm[2], redm[3]));

    float sum = 0.f;
#pragma unroll
    for (int i = 0; i < 32; ++i) {
        v[i] = __expf(v[i] - mx);
        sum += v[i];
    }
#pragma unroll
    for (int off = 32; off; off >>= 1) sum += __shfl_xor(sum, off);
    if (l == 0) reds[w] = sum;
    __syncthreads();
    sum = reds[0] + reds[1] + reds[2] + reds[3];
    float inv = 1.f / sum;

    u16* p = P + row * SEQ;
#pragma unroll
    for (int i = 0; i < 8; ++i) {
        u16x4 o;
#pragma unroll
        for (int j = 0; j < 4; ++j) o[j] = f2bf(v[i * 4 + j] * inv);
        *(u16x4*)&p[4 * (t + i * 256)] = o;
    }
}

// ---------------------------------------------------------------------------
extern "C" void kernel_launch(void* const* d_in, const int* in_sizes, int n_in,
                              void* d_out, int out_size, void* d_ws, size_t ws_size,
                              hipStream_t stream)
{
    const float* X  = (const float*)d_in[0];
    const float* Wq = (const float*)d_in[1];
    const float* Wk = (const float*)d_in[2];
    float* out = (float*)d_out;
    char* ws = (char*)d_ws;

    const size_t XE = (size_t)SEQ * DIM;
    const size_t WE = (size_t)DIM * DIM;

    u16* Xh   = (u16*)ws;
    u16* Xl   = Xh + XE;
    u16* XhT  = Xl + XE;
    u16* XlT  = XhT + XE;
    u16* WqhT = XlT + XE;
    u16* WqlT = WqhT + WE;
    u16* WkhT = WqlT + WE;
    u16* WklT = WkhT + WE;
    u16* Qh   = WklT + WE;
    u16* Ql   = Qh + XE;
    u16* Kh   = Ql + XE;
    u16* Kl   = Kh + XE;
    char* dyn = (char*)(Kl + XE);

    size_t fixed = (size_t)(dyn - ws);
    size_t avail = ws_size > fixed ? ws_size - fixed : 0;

    // 1) splits
    split_kernel<true ><<<dim3(DIM / 32, SEQ / 32), 256, 0, stream>>>(X, SEQ, DIM, Xh, Xl, XhT, XlT);
    split_kernel<false><<<dim3(DIM / 32, DIM / 32), 256, 0, stream>>>(Wq, DIM, DIM, nullptr, nullptr, WqhT, WqlT);
    split_kernel<false><<<dim3(DIM / 32, DIM / 32), 256, 0, stream>>>(Wk, DIM, DIM, nullptr, nullptr, WkhT, WklT);

    // 2) projections: Q = X@Wq, K = X@Wk  (fp32-accurate, written as hi/lo bf16)
    gemm_nt<3, 1><<<dim3(DIM / BN, SEQ / BM), 256, 0, stream>>>(
        Xh, Xl, WqhT, WqlT, SEQ, DIM, DIM, nullptr, Qh, Ql);
    gemm_nt<3, 1><<<dim3(DIM / BN, SEQ / BM), 256, 0, stream>>>(
        Xh, Xl, WkhT, WklT, SEQ, DIM, DIM, nullptr, Kh, Kl);

    const size_t PFULL = (size_t)SEQ * SEQ * sizeof(u16);     // 128 MB
    if (avail >= PFULL + (size_t)128 * SEQ * sizeof(float)) {
        // full-P mode: chunked QK^T+softmax into full P, then ONE PV (512 blocks)
        u16*   Pfull = (u16*)dyn;
        float* Sbuf  = (float*)(dyn + PFULL);
        size_t srem = avail - PFULL;
        long long chll = (long long)(srem / ((size_t)SEQ * sizeof(float)));
        int CH = chll > SEQ ? SEQ : (int)chll;
        CH &= ~127;
        if (CH < 128) CH = 128;

        for (int r0 = 0; r0 < SEQ; r0 += CH) {
            int ch = (SEQ - r0 < CH) ? (SEQ - r0) : CH;
            gemm_nt<3, 0><<<dim3(SEQ / BN, ch / BM), 256, 0, stream>>>(
                Qh + (size_t)r0 * DIM, Ql + (size_t)r0 * DIM, Kh, Kl,
                ch, SEQ, DIM, Sbuf, nullptr, nullptr);
            softmax_kernel<<<ch, 256, 0, stream>>>(Sbuf, Pfull + (size_t)r0 * SEQ);
        }
        gemm_nt<2, 0><<<dim3(DIM / BN, SEQ / BM), 256, 0, stream>>>(
            Pfull, nullptr, XhT, XlT, SEQ, DIM, SEQ, out, nullptr, nullptr);
    } else {
        // legacy chunked mode (small workspace)
        size_t perrow = (size_t)SEQ * 6;       // 4B S + 2B P per row
        long long chll = (long long)(avail / perrow);
        int CH = chll > SEQ ? SEQ : (int)chll;
        CH &= ~127;
        if (CH < 128) CH = 128;

        float* Sbuf = (float*)dyn;
        u16*   Pbuf = (u16*)(dyn + (size_t)CH * SEQ * sizeof(float));

        for (int r0 = 0; r0 < SEQ; r0 += CH) {
            int ch = (SEQ - r0 < CH) ? (SEQ - r0) : CH;
            gemm_nt<3, 0><<<dim3(SEQ / BN, ch / BM), 256, 0, stream>>>(
                Qh + (size_t)r0 * DIM, Ql + (size_t)r0 * DIM, Kh, Kl,
                ch, SEQ, DIM, Sbuf, nullptr, nullptr);
            softmax_kernel<<<ch, 256, 0, stream>>>(Sbuf, Pbuf);
            gemm_nt<2, 0><<<dim3(DIM / BN, ch / BM), 256, 0, stream>>>(
                Pbuf, nullptr, XhT, XlT,
                ch, DIM, SEQ, out + (size_t)r0 * DIM, nullptr, nullptr);
        }
    }
}